// Round 1
// baseline (477.334 us; speedup 1.0000x reference)
//
#include <hip/hip_runtime.h>
#include <math.h>

// FourierCrossAttention: B=16, L=S=2048, H=8, E=O=64, M=64 (first 64 rfft modes)
// Pipeline: tables -> DFT(q,k,v) -> QK+tanh -> QKV -> W-transpose -> QKVW(+irfft scale) -> iDFT
// All fp32 this round (tanh sits on |QK|~1e4 values; bf16 would flip tanh signs).

#define NB 16
#define NL 2048
#define NH 8
#define NE 64
#define NM 64
#define NHE 512  // H*E

// ---------------- K0: twiddle tables ----------------
// Tab[t][m]  = (cos(2pi m t/L), -sin(2pi m t/L))   (rfft convention), t-major
// TabT[m][t] = same values, m-major (for iDFT)
__global__ __launch_bounds__(256) void k_tables(float2* __restrict__ Tab,
                                                float2* __restrict__ TabT) {
    int i = blockIdx.x * 256 + threadIdx.x;  // over L*M = 131072
    int t = i >> 6, m = i & 63;
    double ang = (2.0 * 3.14159265358979323846 / (double)NL) * (double)((t * m) & (NL - 1));
    float c = (float)cos(ang);
    float s = (float)sin(ang);
    Tab[t * NM + m] = make_float2(c, -s);
    TabT[(size_t)m * NL + t] = make_float2(c, -s);
}

// ---------------- K1: DFT of q,k,v ----------------
// Xf[b,h,e,m] = sum_t x[b,t,h,e] * Tab[t][m]
// Block: (eg: 16 e'-columns, b, tensor z). 256 thr = 4 k-quarters x (4 eq x 16 mq).
// Thread tile: 4 e' x 4 m, K=512 per quarter, LDS tree-reduce across quarters.
__global__ __launch_bounds__(256) void k_dft(
    const float* __restrict__ q, const float* __restrict__ k, const float* __restrict__ v,
    const float2* __restrict__ Tab,
    float2* __restrict__ Qf, float2* __restrict__ Kf, float2* __restrict__ Vf) {
    const int eg = blockIdx.x;  // 0..31
    const int b  = blockIdx.y;  // 0..15
    const int z  = blockIdx.z;  // 0..2
    const float* __restrict__ in = (z == 0) ? q : ((z == 1) ? k : v);
    float2* __restrict__ out = (z == 0) ? Qf : ((z == 1) ? Kf : Vf);

    const int tid = threadIdx.x;
    const int kq  = tid >> 6;   // k-quarter 0..3
    const int idx = tid & 63;
    const int eqq = idx >> 4;   // 0..3
    const int mq  = idx & 15;   // 0..15
    const int m0  = mq * 4;

    float acc[32];
#pragma unroll
    for (int i = 0; i < 32; ++i) acc[i] = 0.f;

    // row t of this block's 16 floats: in4[t*128 + eqq]
    const float4* __restrict__ in4 =
        (const float4*)(in + (size_t)b * NL * NHE + eg * 16);
    const float4* __restrict__ tab4 = (const float4*)Tab;  // 32 f4 per t-row

    const int tbase = kq * 512;
#pragma unroll 2
    for (int tt = 0; tt < 512; ++tt) {
        const int t = tbase + tt;
        float4 a4  = in4[(size_t)t * 128 + eqq];
        float4 c01 = tab4[(size_t)t * 32 + mq * 2];
        float4 c23 = tab4[(size_t)t * 32 + mq * 2 + 1];
        float av[4] = {a4.x, a4.y, a4.z, a4.w};
        float cs[8] = {c01.x, c01.y, c01.z, c01.w, c23.x, c23.y, c23.z, c23.w};
#pragma unroll
        for (int e = 0; e < 4; ++e) {
#pragma unroll
            for (int m = 0; m < 4; ++m) {
                acc[(e * 4 + m) * 2 + 0] += av[e] * cs[m * 2 + 0];
                acc[(e * 4 + m) * 2 + 1] += av[e] * cs[m * 2 + 1];
            }
        }
    }

    __shared__ float red[3 * 64 * 33];
    if (kq > 0) {
        float* r = &red[(kq - 1) * 64 * 33 + idx * 33];
#pragma unroll
        for (int i = 0; i < 32; ++i) r[i] = acc[i];
    }
    __syncthreads();
    if (kq == 0) {
#pragma unroll
        for (int p = 0; p < 3; ++p) {
            const float* r = &red[p * 64 * 33 + idx * 33];
#pragma unroll
            for (int i = 0; i < 32; ++i) acc[i] += r[i];
        }
#pragma unroll
        for (int e = 0; e < 4; ++e) {
            int ep = eg * 16 + eqq * 4 + e;
            int h = ep >> 6, ee = ep & 63;
            float2* o = out + (((size_t)(b * NH + h) * NE + ee) * NM + m0);
            float4 s0 = make_float4(acc[(e * 4 + 0) * 2], acc[(e * 4 + 0) * 2 + 1],
                                    acc[(e * 4 + 1) * 2], acc[(e * 4 + 1) * 2 + 1]);
            float4 s1 = make_float4(acc[(e * 4 + 2) * 2], acc[(e * 4 + 2) * 2 + 1],
                                    acc[(e * 4 + 3) * 2], acc[(e * 4 + 3) * 2 + 1]);
            ((float4*)o)[0] = s0;
            ((float4*)o)[1] = s1;
        }
    }
}

// ---------------- K2: QK = sum_e Qf[e,x]*Kf[e,y]; tanh re/im ----------------
// Block: (bh, xhalf). Thread tile 4x*2y. LDS: Qs[64e][32x], Ks[64e][64y].
__global__ __launch_bounds__(256) void k_qk(
    const float2* __restrict__ Qf, const float2* __restrict__ Kf,
    float2* __restrict__ QKt) {
    const int bh = blockIdx.x;  // 0..127
    const int xh = blockIdx.y;  // 0..1
    const int tid = threadIdx.x;
    __shared__ float2 Qs[64 * 34];
    __shared__ float2 Ks[64 * 66];

    const float2* Qbase = Qf + (size_t)bh * (NE * NM);
    const float2* Kbase = Kf + (size_t)bh * (NE * NM);
#pragma unroll
    for (int j = 0; j < 4; ++j) {
        int n = tid + j * 256;  // 1024 f4
        int e = n >> 4, c = n & 15;
        float4 val = ((const float4*)(Qbase + e * NM + xh * 32))[c];
        *((float4*)&Qs[e * 34 + c * 2]) = val;
    }
#pragma unroll
    for (int j = 0; j < 8; ++j) {
        int n = tid + j * 256;  // 2048 f4
        int e = n >> 5, c = n & 31;
        float4 val = ((const float4*)(Kbase + e * NM))[c];
        *((float4*)&Ks[e * 66 + c * 2]) = val;
    }
    __syncthreads();

    const int yq = tid & 31, xq = tid >> 5;  // y0=2yq, x0=4xq
    float accr[4][2], acci[4][2];
#pragma unroll
    for (int i = 0; i < 4; ++i)
#pragma unroll
        for (int j = 0; j < 2; ++j) { accr[i][j] = 0.f; acci[i][j] = 0.f; }

    for (int e = 0; e < 64; ++e) {
        float4 qa = *((float4*)&Qs[e * 34 + xq * 4]);
        float4 qb = *((float4*)&Qs[e * 34 + xq * 4 + 2]);
        float4 kk = *((float4*)&Ks[e * 66 + yq * 2]);
        float qr[4] = {qa.x, qa.z, qb.x, qb.z};
        float qi[4] = {qa.y, qa.w, qb.y, qb.w};
        float kr[2] = {kk.x, kk.z};
        float ki[2] = {kk.y, kk.w};
#pragma unroll
        for (int i = 0; i < 4; ++i) {
#pragma unroll
            for (int j = 0; j < 2; ++j) {
                accr[i][j] += qr[i] * kr[j] - qi[i] * ki[j];
                acci[i][j] += qr[i] * ki[j] + qi[i] * kr[j];
            }
        }
    }
    const int x0 = xh * 32 + xq * 4;
#pragma unroll
    for (int i = 0; i < 4; ++i) {
        float4 sv = make_float4(tanhf(accr[i][0]), tanhf(acci[i][0]),
                                tanhf(accr[i][1]), tanhf(acci[i][1]));
        *((float4*)&QKt[(size_t)bh * 4096 + (x0 + i) * 64 + yq * 2]) = sv;
    }
}

// ---------------- K3: QKV[e,x] = sum_y Vf[e,y]*QKt[x,y] ----------------
// Block: (bh, ehalf). Thread tile 2e*4x. LDS: Vs[32e][64y], Ps[64x][64y].
__global__ __launch_bounds__(256) void k_qkv(
    const float2* __restrict__ Vf, const float2* __restrict__ QKt,
    float2* __restrict__ QKV) {
    const int bh = blockIdx.x;
    const int eh = blockIdx.y;
    const int tid = threadIdx.x;
    __shared__ float2 Vs[32 * 66];
    __shared__ float2 Ps[64 * 66];

    const float2* Vbase = Vf + (size_t)bh * (NE * NM) + eh * 32 * NM;
    const float2* Pbase = QKt + (size_t)bh * 4096;
#pragma unroll
    for (int j = 0; j < 4; ++j) {
        int n = tid + j * 256;  // 1024 f4
        int r = n >> 5, c = n & 31;
        float4 val = ((const float4*)(Vbase + r * NM))[c];
        *((float4*)&Vs[r * 66 + c * 2]) = val;
    }
#pragma unroll
    for (int j = 0; j < 8; ++j) {
        int n = tid + j * 256;
        int r = n >> 5, c = n & 31;
        float4 val = ((const float4*)(Pbase + r * NM))[c];
        *((float4*)&Ps[r * 66 + c * 2]) = val;
    }
    __syncthreads();

    const int xq = tid & 15, eq2 = tid >> 4;
    const int x0 = xq * 4, e0 = eq2 * 2;
    float accr[2][4], acci[2][4];
#pragma unroll
    for (int i = 0; i < 2; ++i)
#pragma unroll
        for (int j = 0; j < 4; ++j) { accr[i][j] = 0.f; acci[i][j] = 0.f; }

    for (int yy = 0; yy < 64; ++yy) {
        float2 v0 = Vs[(e0 + 0) * 66 + yy];
        float2 v1 = Vs[(e0 + 1) * 66 + yy];
        float2 p0 = Ps[(x0 + 0) * 66 + yy];
        float2 p1 = Ps[(x0 + 1) * 66 + yy];
        float2 p2 = Ps[(x0 + 2) * 66 + yy];
        float2 p3 = Ps[(x0 + 3) * 66 + yy];
        float pr[4] = {p0.x, p1.x, p2.x, p3.x};
        float pi[4] = {p0.y, p1.y, p2.y, p3.y};
#pragma unroll
        for (int j = 0; j < 4; ++j) {
            accr[0][j] += v0.x * pr[j] - v0.y * pi[j];
            acci[0][j] += v0.x * pi[j] + v0.y * pr[j];
            accr[1][j] += v1.x * pr[j] - v1.y * pi[j];
            acci[1][j] += v1.x * pi[j] + v1.y * pr[j];
        }
    }
#pragma unroll
    for (int e = 0; e < 2; ++e) {
        float2* obase = QKV + (size_t)bh * 4096 + (eh * 32 + e0 + e) * 64 + x0;
        float4 s0 = make_float4(accr[e][0], acci[e][0], accr[e][1], acci[e][1]);
        float4 s1 = make_float4(accr[e][2], acci[e][2], accr[e][3], acci[e][3]);
        ((float4*)obase)[0] = s0;
        ((float4*)obase)[1] = s1;
    }
}

// ---------------- K4a: transpose W -> Wt[h][x][e][o] ----------------
__global__ __launch_bounds__(256) void k_wt(
    const float* __restrict__ wr, const float* __restrict__ wi,
    float2* __restrict__ Wt) {
    const int e = blockIdx.x, h = blockIdx.y;
    const int tid = threadIdx.x;
    __shared__ float lr[64 * 68];
    __shared__ float li[64 * 68];
    const float* rbase = wr + (size_t)(h * NE + e) * NE * NM;  // [o][x]
    const float* ibase = wi + (size_t)(h * NE + e) * NE * NM;
#pragma unroll
    for (int j = 0; j < 4; ++j) {
        int n = tid + j * 256;  // 1024 f4
        int o = n >> 4, x4 = n & 15;
        float4 r4 = ((const float4*)(rbase + o * NM))[x4];
        float4 i4 = ((const float4*)(ibase + o * NM))[x4];
        *((float4*)&lr[o * 68 + x4 * 4]) = r4;
        *((float4*)&li[o * 68 + x4 * 4]) = i4;
    }
    __syncthreads();
#pragma unroll
    for (int j = 0; j < 16; ++j) {
        int n = tid + j * 256;  // 4096 outputs
        int x = n >> 6, o = n & 63;
        Wt[((size_t)(h * NM + x) * NE + e) * NE + o] =
            make_float2(lr[o * 68 + x], li[o * 68 + x]);
    }
}

// ---------------- K4: QKVW[o,x] = sum_e QKV[e,x]*W[e,o,x], scaled for irfft ----------------
// Block: (x, h). Lanes = o (coalesced Wt), 4 batches per thread. QKV loads wave-uniform.
__global__ __launch_bounds__(256) void k_qkvw(
    const float2* __restrict__ QKV, const float2* __restrict__ Wt,
    float2* __restrict__ QKVWs) {
    const int x = blockIdx.x, h = blockIdx.y;
    const int tid = threadIdx.x;
    const int o = tid & 63, bq = tid >> 6;
    float accr[4], acci[4];
#pragma unroll
    for (int j = 0; j < 4; ++j) { accr[j] = 0.f; acci[j] = 0.f; }

    const float2* wbase = Wt + (size_t)(h * NM + x) * NE * NE + o;
    for (int e = 0; e < 64; ++e) {
        float2 w = wbase[(size_t)e * NE];
#pragma unroll
        for (int j = 0; j < 4; ++j) {
            int b = bq * 4 + j;
            float2 a = QKV[((size_t)(b * NH + h) * NE + e) * NM + x];
            accr[j] += a.x * w.x - a.y * w.y;
            acci[j] += a.x * w.y + a.y * w.x;
        }
    }
    const float sc = (x == 0) ? (1.f / NL) : (2.f / NL);
#pragma unroll
    for (int j = 0; j < 4; ++j) {
        int b = bq * 4 + j;
        QKVWs[((size_t)(b * NH + h) * NM + x) * NE + o] =
            make_float2(accr[j] * sc, acci[j] * sc);
    }
}

// ---------------- K5: iDFT + transpose to [B,L,H,O] ----------------
// y[b,t,h,o] = sum_x ( XsR*cos - XsI*sin ), scale already folded into Xs.
// Block: (t-tile 64, bh). Thread tile 4t*4o. TabT read from L2 (no reuse in-block).
__global__ __launch_bounds__(256) void k_idft(
    const float2* __restrict__ QKVWs, const float2* __restrict__ TabT,
    float* __restrict__ yout) {
    const int tt = blockIdx.x;   // 0..31
    const int bh = blockIdx.y;   // 0..127
    const int b = bh >> 3, h = bh & 7;
    const int tid = threadIdx.x;
    const int t0 = tt * 64;
    __shared__ float2 Xs[64 * 66];  // [x][o]

#pragma unroll
    for (int j = 0; j < 8; ++j) {
        int n = tid + j * 256;  // 2048 f4
        int xr = n >> 5, c = n & 31;
        float4 v4 = ((const float4*)(QKVWs + (size_t)bh * 4096 + xr * 64))[c];
        *((float4*)&Xs[xr * 66 + c * 2]) = v4;
    }
    __syncthreads();

    const int to = tid & 15, tq = tid >> 4;
    const int o0 = to * 4, tl0 = tq * 4;
    float accv[4][4];
#pragma unroll
    for (int i = 0; i < 4; ++i)
#pragma unroll
        for (int j = 0; j < 4; ++j) accv[i][j] = 0.f;

    const float4* tab4 = (const float4*)TabT;  // row x: 1024 f4
    for (int x = 0; x < 64; ++x) {
        float4 ta = tab4[(size_t)x * 1024 + (t0 + tl0) / 2];
        float4 tb = tab4[(size_t)x * 1024 + (t0 + tl0) / 2 + 1];
        float4 xa = *((float4*)&Xs[x * 66 + o0]);
        float4 xb = *((float4*)&Xs[x * 66 + o0 + 2]);
        float xrr[4] = {xa.x, xa.z, xb.x, xb.z};
        float xii[4] = {xa.y, xa.w, xb.y, xb.w};
        float tc[8] = {ta.x, ta.y, ta.z, ta.w, tb.x, tb.y, tb.z, tb.w};
#pragma unroll
        for (int it = 0; it < 4; ++it) {
            float c = tc[it * 2 + 0];
            float ns = tc[it * 2 + 1];  // = -sin
#pragma unroll
            for (int io = 0; io < 4; ++io) {
                accv[it][io] += c * xrr[io] + ns * xii[io];
            }
        }
    }
#pragma unroll
    for (int it = 0; it < 4; ++it) {
        int t = t0 + tl0 + it;
        float4 st = make_float4(accv[it][0], accv[it][1], accv[it][2], accv[it][3]);
        *((float4*)(yout + (((size_t)b * NL + t) * NH + h) * NE + o0)) = st;
    }
}

extern "C" void kernel_launch(void* const* d_in, const int* in_sizes, int n_in,
                              void* d_out, int out_size, void* d_ws, size_t ws_size,
                              hipStream_t stream) {
    const float* q  = (const float*)d_in[0];
    const float* k  = (const float*)d_in[1];
    const float* v  = (const float*)d_in[2];
    const float* wr = (const float*)d_in[3];
    const float* wi = (const float*)d_in[4];
    float* out = (float*)d_out;

    // workspace layout (float2 units)
    float2* ws    = (float2*)d_ws;
    float2* Tab   = ws;                  // 131072
    float2* TabT  = Tab + 131072;        // 131072
    float2* Qf    = TabT + 131072;       // 524288 each below
    float2* Kf    = Qf + 524288;
    float2* Vf    = Kf + 524288;
    float2* QKt   = Vf + 524288;
    float2* QKV   = QKt + 524288;
    float2* Wt    = QKV + 524288;        // 2097152
    float2* QKVWs = Wt + 2097152;        // 524288
    // total = 5,505,024 float2 = 44 MB

    hipLaunchKernelGGL(k_tables, dim3(512), dim3(256), 0, stream, Tab, TabT);
    hipLaunchKernelGGL(k_dft, dim3(32, 16, 3), dim3(256), 0, stream,
                       q, k, v, Tab, Qf, Kf, Vf);
    hipLaunchKernelGGL(k_qk, dim3(128, 2), dim3(256), 0, stream, Qf, Kf, QKt);
    hipLaunchKernelGGL(k_qkv, dim3(128, 2), dim3(256), 0, stream, Vf, QKt, QKV);
    hipLaunchKernelGGL(k_wt, dim3(64, 8), dim3(256), 0, stream, wr, wi, Wt);
    hipLaunchKernelGGL(k_qkvw, dim3(64, 8), dim3(256), 0, stream, QKV, Wt, QKVWs);
    hipLaunchKernelGGL(k_idft, dim3(32, 128), dim3(256), 0, stream, QKVWs, TabT, out);
}

// Round 2
// 228.699 us; speedup vs baseline: 2.0872x; 2.0872x over previous
//
#include <hip/hip_runtime.h>
#include <math.h>

// FourierCrossAttention: B=16, L=S=2048, H=8, E=O=64, M=64 (first 64 rfft modes)
// Pipeline: tables -> MFMA split-bf16 DFT(q,k,v) -> QK+tanh -> QKV -> Wt -> QKVW -> iDFT
// DFT uses 3-product hi/lo bf16 split (XhTh + XhTl + XlTh) for fp32-grade accuracy.

#define NB 16
#define NL 2048
#define NH 8
#define NE 64
#define NM 64
#define NHE 512  // H*E

typedef unsigned short ushort_t;
typedef __attribute__((ext_vector_type(8))) short short8;
typedef __attribute__((ext_vector_type(4))) float f32x4;

// table layout: [64 ksteps][128 m'][40 shorts] (shorts 0..31 = t within kstep, 32..39 pad=0)
#define TW_ELEMS (64 * 128 * 40)

__device__ inline void gld_lds16(const void* g, void* l) {
    __builtin_amdgcn_global_load_lds((const __attribute__((address_space(1))) unsigned int*)g,
                                     (__attribute__((address_space(3))) unsigned int*)l, 16, 0, 0);
}

// ---------------- K0a: bf16 hi/lo twiddle tables (padded staging layout) ----------------
__global__ __launch_bounds__(256) void k_tables_gemm(ushort_t* __restrict__ Twh,
                                                     ushort_t* __restrict__ Twl) {
    int i = blockIdx.x * 256 + threadIdx.x;  // over 64*128*40 = 327680
    if (i >= TW_ELEMS) return;
    int s = i % 40;
    int rest = i / 40;
    int mp = rest & 127;
    int ks = rest >> 7;
    ushort_t h = 0, l = 0;
    if (s < 32) {
        int t = ks * 32 + s;
        int m = mp >> 1;
        double ang = (2.0 * 3.14159265358979323846 / (double)NL) * (double)((m * t) & (NL - 1));
        double cd = (mp & 1) ? -sin(ang) : cos(ang);
        float cf = (float)cd;
        unsigned cb = __float_as_uint(cf);
        unsigned hb = cb & 0xffff0000u;
        h = (ushort_t)(cb >> 16);
        float lo = cf - __uint_as_float(hb);
        unsigned lb = __float_as_uint(lo);
        unsigned r = lb + 0x7fffu + ((lb >> 16) & 1u);
        l = (ushort_t)(r >> 16);
    }
    Twh[i] = h;
    Twl[i] = l;
}

// ---------------- K0b: fp32 iDFT table TabT[m][t] = (cos, -sin) ----------------
__global__ __launch_bounds__(256) void k_tabT(float2* __restrict__ TabT) {
    int i = blockIdx.x * 256 + threadIdx.x;  // over M*L = 131072
    int t = i >> 6, m = i & 63;
    double ang = (2.0 * 3.14159265358979323846 / (double)NL) * (double)((t * m) & (NL - 1));
    TabT[(size_t)m * NL + t] = make_float2((float)cos(ang), -(float)sin(ang));
}

// ---------------- K1: MFMA DFT ----------------
// C[he, m'] = sum_t X[t, he] * Tw[t, m'], per (b, z). 3-product hi/lo bf16 split.
// Block: 64 he x 128 m', BK=32, 64 K-steps, double-buffered LDS.
// A staged as raw fp32 [32t][67he] (reg-staged, transposed read); B via global_load_lds.
__global__ __launch_bounds__(256, 2) void k_gemm(
    const float* __restrict__ q, const float* __restrict__ k, const float* __restrict__ v,
    const ushort_t* __restrict__ Twh, const ushort_t* __restrict__ Twl,
    float* __restrict__ Qf, float* __restrict__ Kf, float* __restrict__ Vf) {
    const int bx = blockIdx.x;  // he-group 0..7
    const int b  = blockIdx.y;  // 0..15
    const int z  = blockIdx.z;  // 0..2
    const float* __restrict__ in = (z == 0) ? q : ((z == 1) ? k : v);
    float* __restrict__ out = (z == 0) ? Qf : ((z == 1) ? Kf : Vf);

    const int tid  = threadIdx.x;
    const int wid  = tid >> 6;
    const int lane = tid & 63;
    const int lr   = lane & 15;
    const int lg   = lane >> 4;
    const int wy   = wid >> 1;  // he-half (0..1) -> +32
    const int wx   = wid & 1;   // m-half  (0..1) -> +64
    const int he0  = bx * 64;

    __shared__ float    As[2][32 * 67];
    __shared__ ushort_t Bh[2][128 * 40];
    __shared__ ushort_t Bl[2][128 * 40];

    // staging thread mapping (A): idx = tid + r*256 -> he4 = idx&15, tt = idx>>4
    const int he4a = tid & 15;
    const int tt0  = tid >> 4;        // r=0: tt = tt0 ; r=1: tt = tt0 + 16
    const size_t in_row_base = ((size_t)b * NL) * NHE + he0 + he4a * 4;

    f32x4 acc[2][4];
#pragma unroll
    for (int f = 0; f < 2; ++f)
#pragma unroll
        for (int j = 0; j < 4; ++j) acc[f][j] = (f32x4){0.f, 0.f, 0.f, 0.f};

    // ---- prologue: stage kstep 0 into buffer 0 ----
    {
        float4 av0 = *(const float4*)(in + in_row_base + (size_t)(0 * 32 + tt0) * NHE);
        float4 av1 = *(const float4*)(in + in_row_base + (size_t)(0 * 32 + tt0 + 16) * NHE);
        const ushort_t* gh = Twh;  // kstep 0
        const ushort_t* gl = Twl;
        for (int u = tid; u < 640; u += 256) {
            gld_lds16(gh + u * 8, &Bh[0][u * 8]);
            gld_lds16(gl + u * 8, &Bl[0][u * 8]);
        }
        float* d0 = &As[0][tt0 * 67 + he4a * 4];
        d0[0] = av0.x; d0[1] = av0.y; d0[2] = av0.z; d0[3] = av0.w;
        float* d1 = &As[0][(tt0 + 16) * 67 + he4a * 4];
        d1[0] = av1.x; d1[1] = av1.y; d1[2] = av1.z; d1[3] = av1.w;
    }

    int cur = 0;
    for (int ks = 0; ks < 64; ++ks) {
        __syncthreads();
        const bool more = (ks + 1) < 64;
        float4 av0, av1;
        if (more) {
            const size_t tb = (size_t)(ks + 1) * 32;
            av0 = *(const float4*)(in + in_row_base + (tb + tt0) * NHE);
            av1 = *(const float4*)(in + in_row_base + (tb + tt0 + 16) * NHE);
            const ushort_t* gh = Twh + (size_t)(ks + 1) * (128 * 40);
            const ushort_t* gl = Twl + (size_t)(ks + 1) * (128 * 40);
            ushort_t* lbh = &Bh[cur ^ 1][0];
            ushort_t* lbl = &Bl[cur ^ 1][0];
            for (int u = tid; u < 640; u += 256) {
                gld_lds16(gh + u * 8, lbh + u * 8);
                gld_lds16(gl + u * 8, lbl + u * 8);
            }
        }

        // ---- compute on buffer cur ----
        const float* ac = &As[cur][0];
        const ushort_t* bhc = &Bh[cur][0];
        const ushort_t* blc = &Bl[cur][0];

        short8 ah[2], al[2];
#pragma unroll
        for (int f = 0; f < 2; ++f) {
            const int he = wy * 32 + f * 16 + lr;
            float xa[8];
#pragma unroll
            for (int j = 0; j < 8; ++j) xa[j] = ac[(8 * lg + j) * 67 + he];
            union { unsigned u[4]; short8 s; } uh, ul;
#pragma unroll
            for (int p = 0; p < 4; ++p) {
                unsigned b0 = __float_as_uint(xa[2 * p]);
                unsigned b1 = __float_as_uint(xa[2 * p + 1]);
                uh.u[p] = (b0 >> 16) | (b1 & 0xffff0000u);
                float l0 = xa[2 * p]     - __uint_as_float(b0 & 0xffff0000u);
                float l1 = xa[2 * p + 1] - __uint_as_float(b1 & 0xffff0000u);
                unsigned lw;
                asm("v_cvt_pk_bf16_f32 %0, %1, %2" : "=v"(lw) : "v"(l0), "v"(l1));
                ul.u[p] = lw;
            }
            ah[f] = uh.s;
            al[f] = ul.s;
        }

        short8 bh8[4], bl8[4];
#pragma unroll
        for (int j = 0; j < 4; ++j) {
            const int mp = wx * 64 + j * 16 + lr;
            bh8[j] = *(const short8*)&bhc[mp * 40 + 8 * lg];
            bl8[j] = *(const short8*)&blc[mp * 40 + 8 * lg];
        }

#pragma unroll
        for (int f = 0; f < 2; ++f) {
#pragma unroll
            for (int j = 0; j < 4; ++j) {
                acc[f][j] = __builtin_amdgcn_mfma_f32_16x16x32_bf16(ah[f], bh8[j], acc[f][j], 0, 0, 0);
                acc[f][j] = __builtin_amdgcn_mfma_f32_16x16x32_bf16(ah[f], bl8[j], acc[f][j], 0, 0, 0);
                acc[f][j] = __builtin_amdgcn_mfma_f32_16x16x32_bf16(al[f], bh8[j], acc[f][j], 0, 0, 0);
            }
        }

        if (more) {
            float* d0 = &As[cur ^ 1][tt0 * 67 + he4a * 4];
            d0[0] = av0.x; d0[1] = av0.y; d0[2] = av0.z; d0[3] = av0.w;
            float* d1 = &As[cur ^ 1][(tt0 + 16) * 67 + he4a * 4];
            d1[0] = av1.x; d1[1] = av1.y; d1[2] = av1.z; d1[3] = av1.w;
        }
        cur ^= 1;
    }

    // ---- epilogue: C[he][m'] is Qf viewed as float [b*512+he][128] ----
#pragma unroll
    for (int f = 0; f < 2; ++f) {
#pragma unroll
        for (int j = 0; j < 4; ++j) {
            const int col = wx * 64 + j * 16 + lr;
#pragma unroll
            for (int r = 0; r < 4; ++r) {
                const int he = he0 + wy * 32 + f * 16 + 4 * lg + r;
                out[((size_t)b * NHE + he) * 128 + col] = acc[f][j][r];
            }
        }
    }
}

// ---------------- K2: QK = sum_e Qf[e,x]*Kf[e,y]; tanh re/im ----------------
__global__ __launch_bounds__(256) void k_qk(
    const float2* __restrict__ Qf, const float2* __restrict__ Kf,
    float2* __restrict__ QKt) {
    const int bh = blockIdx.x;  // 0..127
    const int xh = blockIdx.y;  // 0..1
    const int tid = threadIdx.x;
    __shared__ float2 Qs[64 * 34];
    __shared__ float2 Ks[64 * 66];

    const float2* Qbase = Qf + (size_t)bh * (NE * NM);
    const float2* Kbase = Kf + (size_t)bh * (NE * NM);
#pragma unroll
    for (int j = 0; j < 4; ++j) {
        int n = tid + j * 256;  // 1024 f4
        int e = n >> 4, c = n & 15;
        float4 val = ((const float4*)(Qbase + e * NM + xh * 32))[c];
        *((float4*)&Qs[e * 34 + c * 2]) = val;
    }
#pragma unroll
    for (int j = 0; j < 8; ++j) {
        int n = tid + j * 256;  // 2048 f4
        int e = n >> 5, c = n & 31;
        float4 val = ((const float4*)(Kbase + e * NM))[c];
        *((float4*)&Ks[e * 66 + c * 2]) = val;
    }
    __syncthreads();

    const int yq = tid & 31, xq = tid >> 5;  // y0=2yq, x0=4xq
    float accr[4][2], acci[4][2];
#pragma unroll
    for (int i = 0; i < 4; ++i)
#pragma unroll
        for (int j = 0; j < 2; ++j) { accr[i][j] = 0.f; acci[i][j] = 0.f; }

    for (int e = 0; e < 64; ++e) {
        float4 qa = *((float4*)&Qs[e * 34 + xq * 4]);
        float4 qb = *((float4*)&Qs[e * 34 + xq * 4 + 2]);
        float4 kk = *((float4*)&Ks[e * 66 + yq * 2]);
        float qr[4] = {qa.x, qa.z, qb.x, qb.z};
        float qi[4] = {qa.y, qa.w, qb.y, qb.w};
        float kr[2] = {kk.x, kk.z};
        float ki[2] = {kk.y, kk.w};
#pragma unroll
        for (int i = 0; i < 4; ++i) {
#pragma unroll
            for (int j = 0; j < 2; ++j) {
                accr[i][j] += qr[i] * kr[j] - qi[i] * ki[j];
                acci[i][j] += qr[i] * ki[j] + qi[i] * kr[j];
            }
        }
    }
    const int x0 = xh * 32 + xq * 4;
#pragma unroll
    for (int i = 0; i < 4; ++i) {
        float4 sv = make_float4(tanhf(accr[i][0]), tanhf(acci[i][0]),
                                tanhf(accr[i][1]), tanhf(acci[i][1]));
        *((float4*)&QKt[(size_t)bh * 4096 + (x0 + i) * 64 + yq * 2]) = sv;
    }
}

// ---------------- K3: QKV[e,x] = sum_y Vf[e,y]*QKt[x,y] ----------------
__global__ __launch_bounds__(256) void k_qkv(
    const float2* __restrict__ Vf, const float2* __restrict__ QKt,
    float2* __restrict__ QKV) {
    const int bh = blockIdx.x;
    const int eh = blockIdx.y;
    const int tid = threadIdx.x;
    __shared__ float2 Vs[32 * 66];
    __shared__ float2 Ps[64 * 66];

    const float2* Vbase = Vf + (size_t)bh * (NE * NM) + eh * 32 * NM;
    const float2* Pbase = QKt + (size_t)bh * 4096;
#pragma unroll
    for (int j = 0; j < 4; ++j) {
        int n = tid + j * 256;  // 1024 f4
        int r = n >> 5, c = n & 31;
        float4 val = ((const float4*)(Vbase + r * NM))[c];
        *((float4*)&Vs[r * 66 + c * 2]) = val;
    }
#pragma unroll
    for (int j = 0; j < 8; ++j) {
        int n = tid + j * 256;
        int r = n >> 5, c = n & 31;
        float4 val = ((const float4*)(Pbase + r * NM))[c];
        *((float4*)&Ps[r * 66 + c * 2]) = val;
    }
    __syncthreads();

    const int xq = tid & 15, eq2 = tid >> 4;
    const int x0 = xq * 4, e0 = eq2 * 2;
    float accr[2][4], acci[2][4];
#pragma unroll
    for (int i = 0; i < 2; ++i)
#pragma unroll
        for (int j = 0; j < 4; ++j) { accr[i][j] = 0.f; acci[i][j] = 0.f; }

    for (int yy = 0; yy < 64; ++yy) {
        float2 v0 = Vs[(e0 + 0) * 66 + yy];
        float2 v1 = Vs[(e0 + 1) * 66 + yy];
        float2 p0 = Ps[(x0 + 0) * 66 + yy];
        float2 p1 = Ps[(x0 + 1) * 66 + yy];
        float2 p2 = Ps[(x0 + 2) * 66 + yy];
        float2 p3 = Ps[(x0 + 3) * 66 + yy];
        float pr[4] = {p0.x, p1.x, p2.x, p3.x};
        float pi[4] = {p0.y, p1.y, p2.y, p3.y};
#pragma unroll
        for (int j = 0; j < 4; ++j) {
            accr[0][j] += v0.x * pr[j] - v0.y * pi[j];
            acci[0][j] += v0.x * pi[j] + v0.y * pr[j];
            accr[1][j] += v1.x * pr[j] - v1.y * pi[j];
            acci[1][j] += v1.x * pi[j] + v1.y * pr[j];
        }
    }
#pragma unroll
    for (int e = 0; e < 2; ++e) {
        float2* obase = QKV + (size_t)bh * 4096 + (eh * 32 + e0 + e) * 64 + x0;
        float4 s0 = make_float4(accr[e][0], acci[e][0], accr[e][1], acci[e][1]);
        float4 s1 = make_float4(accr[e][2], acci[e][2], accr[e][3], acci[e][3]);
        ((float4*)obase)[0] = s0;
        ((float4*)obase)[1] = s1;
    }
}

// ---------------- K4a: transpose W -> Wt[h][x][e][o] ----------------
__global__ __launch_bounds__(256) void k_wt(
    const float* __restrict__ wr, const float* __restrict__ wi,
    float2* __restrict__ Wt) {
    const int e = blockIdx.x, h = blockIdx.y;
    const int tid = threadIdx.x;
    __shared__ float lr[64 * 68];
    __shared__ float li[64 * 68];
    const float* rbase = wr + (size_t)(h * NE + e) * NE * NM;  // [o][x]
    const float* ibase = wi + (size_t)(h * NE + e) * NE * NM;
#pragma unroll
    for (int j = 0; j < 4; ++j) {
        int n = tid + j * 256;  // 1024 f4
        int o = n >> 4, x4 = n & 15;
        float4 r4 = ((const float4*)(rbase + o * NM))[x4];
        float4 i4 = ((const float4*)(ibase + o * NM))[x4];
        *((float4*)&lr[o * 68 + x4 * 4]) = r4;
        *((float4*)&li[o * 68 + x4 * 4]) = i4;
    }
    __syncthreads();
#pragma unroll
    for (int j = 0; j < 16; ++j) {
        int n = tid + j * 256;  // 4096 outputs
        int x = n >> 6, o = n & 63;
        Wt[((size_t)(h * NM + x) * NE + e) * NE + o] =
            make_float2(lr[o * 68 + x], li[o * 68 + x]);
    }
}

// ---------------- K4: QKVW[o,x] = sum_e QKV[e,x]*W[e,o,x], scaled for irfft ----------------
__global__ __launch_bounds__(256) void k_qkvw(
    const float2* __restrict__ QKV, const float2* __restrict__ Wt,
    float2* __restrict__ QKVWs) {
    const int x = blockIdx.x, h = blockIdx.y;
    const int tid = threadIdx.x;
    const int o = tid & 63, bq = tid >> 6;
    float accr[4], acci[4];
#pragma unroll
    for (int j = 0; j < 4; ++j) { accr[j] = 0.f; acci[j] = 0.f; }

    const float2* wbase = Wt + (size_t)(h * NM + x) * NE * NE + o;
    for (int e = 0; e < 64; ++e) {
        float2 w = wbase[(size_t)e * NE];
#pragma unroll
        for (int j = 0; j < 4; ++j) {
            int b = bq * 4 + j;
            float2 a = QKV[((size_t)(b * NH + h) * NE + e) * NM + x];
            accr[j] += a.x * w.x - a.y * w.y;
            acci[j] += a.x * w.y + a.y * w.x;
        }
    }
    const float sc = (x == 0) ? (1.f / NL) : (2.f / NL);
#pragma unroll
    for (int j = 0; j < 4; ++j) {
        int b = bq * 4 + j;
        QKVWs[((size_t)(b * NH + h) * NM + x) * NE + o] =
            make_float2(accr[j] * sc, acci[j] * sc);
    }
}

// ---------------- K5: iDFT + transpose to [B,L,H,O] ----------------
__global__ __launch_bounds__(256) void k_idft(
    const float2* __restrict__ QKVWs, const float2* __restrict__ TabT,
    float* __restrict__ yout) {
    const int tt = blockIdx.x;   // 0..31
    const int bh = blockIdx.y;   // 0..127
    const int b = bh >> 3, h = bh & 7;
    const int tid = threadIdx.x;
    const int t0 = tt * 64;
    __shared__ float2 Xs[64 * 66];  // [x][o]

#pragma unroll
    for (int j = 0; j < 8; ++j) {
        int n = tid + j * 256;  // 2048 f4
        int xr = n >> 5, c = n & 31;
        float4 v4 = ((const float4*)(QKVWs + (size_t)bh * 4096 + xr * 64))[c];
        *((float4*)&Xs[xr * 66 + c * 2]) = v4;
    }
    __syncthreads();

    const int to = tid & 15, tq = tid >> 4;
    const int o0 = to * 4, tl0 = tq * 4;
    float accv[4][4];
#pragma unroll
    for (int i = 0; i < 4; ++i)
#pragma unroll
        for (int j = 0; j < 4; ++j) accv[i][j] = 0.f;

    const float4* tab4 = (const float4*)TabT;  // row x: 1024 f4
    for (int x = 0; x < 64; ++x) {
        float4 ta = tab4[(size_t)x * 1024 + (t0 + tl0) / 2];
        float4 tb = tab4[(size_t)x * 1024 + (t0 + tl0) / 2 + 1];
        float4 xa = *((float4*)&Xs[x * 66 + o0]);
        float4 xb = *((float4*)&Xs[x * 66 + o0 + 2]);
        float xrr[4] = {xa.x, xa.z, xb.x, xb.z};
        float xii[4] = {xa.y, xa.w, xb.y, xb.w};
        float tc[8] = {ta.x, ta.y, ta.z, ta.w, tb.x, tb.y, tb.z, tb.w};
#pragma unroll
        for (int it = 0; it < 4; ++it) {
            float c = tc[it * 2 + 0];
            float ns = tc[it * 2 + 1];  // = -sin
#pragma unroll
            for (int io = 0; io < 4; ++io) {
                accv[it][io] += c * xrr[io] + ns * xii[io];
            }
        }
    }
#pragma unroll
    for (int it = 0; it < 4; ++it) {
        int t = t0 + tl0 + it;
        float4 st = make_float4(accv[it][0], accv[it][1], accv[it][2], accv[it][3]);
        *((float4*)(yout + (((size_t)b * NL + t) * NH + h) * NE + o0)) = st;
    }
}

extern "C" void kernel_launch(void* const* d_in, const int* in_sizes, int n_in,
                              void* d_out, int out_size, void* d_ws, size_t ws_size,
                              hipStream_t stream) {
    const float* q  = (const float*)d_in[0];
    const float* k  = (const float*)d_in[1];
    const float* v  = (const float*)d_in[2];
    const float* wr = (const float*)d_in[3];
    const float* wi = (const float*)d_in[4];
    float* out = (float*)d_out;

    // workspace layout (bytes)
    char* w = (char*)d_ws;
    ushort_t* Twh = (ushort_t*)w;                       // 655,360 B
    ushort_t* Twl = (ushort_t*)(w + 655360);            // 655,360 B
    float2* TabT  = (float2*)(w + 1310720);             // 1,048,576 B
    float2* Qf    = (float2*)(w + 2359296);             // 4,194,304 B each below
    float2* Kf    = (float2*)(w + 6553600);
    float2* Vf    = (float2*)(w + 10747904);
    float2* QKt   = (float2*)(w + 14942208);
    float2* QKV   = (float2*)(w + 19136512);
    float2* Wt    = (float2*)(w + 23330816);            // 16,777,216 B
    float2* QKVWs = (float2*)(w + 40108032);            // 4,194,304 B
    // total = 44,302,336 B

    hipLaunchKernelGGL(k_tables_gemm, dim3(1280), dim3(256), 0, stream, Twh, Twl);
    hipLaunchKernelGGL(k_tabT, dim3(512), dim3(256), 0, stream, TabT);
    hipLaunchKernelGGL(k_gemm, dim3(8, 16, 3), dim3(256), 0, stream,
                       q, k, v, Twh, Twl, (float*)Qf, (float*)Kf, (float*)Vf);
    hipLaunchKernelGGL(k_qk, dim3(128, 2), dim3(256), 0, stream, Qf, Kf, QKt);
    hipLaunchKernelGGL(k_qkv, dim3(128, 2), dim3(256), 0, stream, Vf, QKt, QKV);
    hipLaunchKernelGGL(k_wt, dim3(64, 8), dim3(256), 0, stream, wr, wi, Wt);
    hipLaunchKernelGGL(k_qkvw, dim3(64, 8), dim3(256), 0, stream, QKV, Wt, QKVWs);
    hipLaunchKernelGGL(k_idft, dim3(32, 128), dim3(256), 0, stream, QKVWs, TabT, out);
}